// Round 8
// baseline (262.886 us; speedup 1.0000x reference)
//
#include <hip/hip_runtime.h>
#include <math.h>

#define D        2048
#define E        64
#define NROWS    16384              // B*S = 4*4096

// ---------------- fused MFMA path geometry ----------------
#define ROWS_PB  32                 // token rows per block
#define BKC      64                 // K per chunk
#define NCH      (D / BKC)          // 32 chunks
#define XBUFB    8192               // one x buffer: [32 rows][64 k] fp32
#define NBUF     4                  // 4-deep ring -> STAGE(c+2) pipeline
// LDS = 4 x 8192 = 32768 B -> 2 blocks/CU (grid-limited), deep DMA pipeline

// lo-term scaling: lo' = (v - fp16(v)) * 2^11 (keeps lo in fp16 NORMAL range).
// Recombine with 2^-11 / 2^-22.
#define LSCALE   2048.0f
#define S1       4.8828125e-4f            // 2^-11
#define S2       2.384185791015625e-7f    // 2^-22

typedef __attribute__((ext_vector_type(8))) _Float16 f16x8;
typedef __attribute__((ext_vector_type(4))) float f32x4;

// W hi/lo split in module globals (512 KB) — d_ws never touched.
__device__ __attribute__((aligned(16))) unsigned short g_whi[(size_t)E * D];
__device__ __attribute__((aligned(16))) unsigned short g_wlo[(size_t)E * D];

__device__ __forceinline__ unsigned short f2h(float f) {
    union { _Float16 h; unsigned short u; } c;
    c.h = (_Float16)f;                 // v_cvt_f16_f32, RNE
    return c.u;
}
__device__ __forceinline__ float h2f(unsigned short u) {
    union { _Float16 h; unsigned short u; } c;
    c.u = u;
    return (float)c.h;
}

__device__ __forceinline__ f16x8 ld_b16(const unsigned short* p) {
    union { uint4 u; f16x8 h; } c;
    c.u = *(const uint4*)p;
    return c.h;
}

// async global->LDS DMA, 16 B/lane. LDS dest = wave-uniform base + lane*16;
// global src per-lane (carries the swizzle). Counted by vmcnt.
__device__ __forceinline__ void dma16(const void* g, void* l) {
    __builtin_amdgcn_global_load_lds(
        (const __attribute__((address_space(1))) unsigned int*)g,
        (__attribute__((address_space(3))) unsigned int*)l,
        16, 0, 0);
}

// scale + split 8 consecutive fp32 into fp16 hi / lo' fragments (in-register)
__device__ __forceinline__ void split8(float4 A, float4 B, float f,
                                       f16x8& hi, f16x8& lo) {
    float v[8] = {A.x * f, A.y * f, A.z * f, A.w * f,
                  B.x * f, B.y * f, B.z * f, B.w * f};
    unsigned int hw[4], lw[4];
#pragma unroll
    for (int j = 0; j < 4; ++j) {
        const unsigned short h0 = f2h(v[2*j]);
        const unsigned short h1 = f2h(v[2*j+1]);
        const unsigned short l0 = f2h((v[2*j]   - h2f(h0)) * LSCALE);
        const unsigned short l1 = f2h((v[2*j+1] - h2f(h1)) * LSCALE);
        hw[j] = (unsigned int)h0 | ((unsigned int)h1 << 16);
        lw[j] = (unsigned int)l0 | ((unsigned int)l1 << 16);
    }
    union { uint4 u; f16x8 h; } ch, cl;
    ch.u = make_uint4(hw[0], hw[1], hw[2], hw[3]); hi = ch.h;
    cl.u = make_uint4(lw[0], lw[1], lw[2], lw[3]); lo = cl.h;
}

// ============ K0: split W (fp32) -> g_whi, g_wlo' (fp16, RNE) ===============
__global__ __launch_bounds__(256)
void w_cvt(const float* __restrict__ W)
{
    const int i = (blockIdx.x * 256 + threadIdx.x) << 3;
    const float4 a = *(const float4*)(W + i);
    const float4 b = *(const float4*)(W + i + 4);
    float vv[8] = {a.x, a.y, a.z, a.w, b.x, b.y, b.z, b.w};
    unsigned int hw[4], lw[4];
#pragma unroll
    for (int j = 0; j < 4; ++j) {
        const unsigned short h0 = f2h(vv[2*j]);
        const unsigned short h1 = f2h(vv[2*j+1]);
        const unsigned short l0 = f2h((vv[2*j]   - h2f(h0)) * LSCALE);
        const unsigned short l1 = f2h((vv[2*j+1] - h2f(h1)) * LSCALE);
        hw[j] = (unsigned int)h0 | ((unsigned int)h1 << 16);
        lw[j] = (unsigned int)l0 | ((unsigned int)l1 << 16);
    }
    *(uint4*)(g_whi + i) = make_uint4(hw[0], hw[1], hw[2], hw[3]);
    *(uint4*)(g_wlo + i) = make_uint4(lw[0], lw[1], lw[2], lw[3]);
}

// ============ K1: counted-vmcnt pipelined fp16-split MFMA + softmax/top2 ====
// Grid 512 x 512 thr (8 waves). Per iter c:
//   s_waitcnt vmcnt(1)  -> own STAGE(c) retired (STAGE(c+1) stays in flight)
//   s_barrier           -> all waves' STAGE(c) landed; buf[(c+2)&3] free
//   W(c) global loads (L1-resident 16KB chunk)  [issued BEFORE the STAGE so
//       compiler W-waits never drain STAGE(c+2): vmcnt retires in order]
//   sched_barrier(0)    -> pin that issue order
//   STAGE(c+2) -> buf[(c+2)&3]   (2-phase-deep; never drained in-loop)
//   compute buf[c&3]: swizzled ds_read x, split8, 8 MFMA
// x LDS layout/swizzle identical to r7 (verified): linear DMA dest +
// pre-swizzled global source, read slot16 ^= (row&7).
__global__ __launch_bounds__(512, 4)
void moe_fused(const float* __restrict__ x,
               const float* __restrict__ scond,
               const int* __restrict__ sidx,
               const float* __restrict__ noise,
               float* __restrict__ dispatch,
               float* __restrict__ probs,
               float* __restrict__ sel)
{
    __shared__ float4 smem_q[NBUF * XBUFB / 16];      // 32768 B
    unsigned char* const sm = (unsigned char*)smem_q;

    const int t = threadIdx.x;
    const int l = t & 63;
    const int w = t >> 6;

    const float factor = 1.0f + 0.1f * scond[sidx[0]];

    // wave / fragment maps (verified)
    const int R  = (w >> 2) << 4;       // wave row base: 0 / 16
    const int CB = (w & 3) << 4;        // wave expert base: 0/16/32/48
    const int fr = l & 15;
    const int fq = l >> 4;
    const int sw = fr & 7;              // read-side swizzle key (row&7)

    const int rowG0 = blockIdx.x * ROWS_PB;

    // DMA source base (pre-swizzled: global col16 = physical slot ^ (row&7))
    const float* xsrc =
        x + (size_t)(rowG0 + (t >> 4)) * D + (((t & 15) ^ ((t >> 4) & 7)) << 2);
    // wave-uniform LDS dest offset (lane*16 added by HW)
    const int wb = w << 10;             // w*1024 bytes

    // W fragment bases (direct global; L2/L1-resident)
    const unsigned short* whb = g_whi + (size_t)(CB + fr) * D + (fq << 3);
    const unsigned short* wlb = g_wlo + (size_t)(CB + fr) * D + (fq << 3);

    f32x4 acch = {0.f,0.f,0.f,0.f};
    f32x4 accm = {0.f,0.f,0.f,0.f};
    f32x4 accl = {0.f,0.f,0.f,0.f};

    // prologue: stage chunks 0 and 1 (loop's top wait/barrier syncs them)
    dma16(xsrc,            sm + 0 * XBUFB + wb);
    dma16(xsrc + 1 * BKC,  sm + 1 * XBUFB + wb);

    for (int c = 0; c < NCH; ++c) {
        // own STAGE(c) retired; keep STAGE(c+1) in flight
        asm volatile("s_waitcnt vmcnt(1)" ::: "memory");
        __builtin_amdgcn_s_barrier();          // all STAGE(c) visible

        // W loads for this chunk (both ks) — BEFORE the next STAGE
        const int kc = c * BKC;
        const f16x8 bh0 = ld_b16(whb + kc);
        const f16x8 bl0 = ld_b16(wlb + kc);
        const f16x8 bh1 = ld_b16(whb + kc + 32);
        const f16x8 bl1 = ld_b16(wlb + kc + 32);
        __builtin_amdgcn_sched_barrier(0);     // pin W-before-STAGE order

        if (c + 2 < NCH)
            dma16(xsrc + (size_t)(c + 2) * BKC, sm + ((c + 2) & 3) * XBUFB + wb);

        const float* xb = (const float*)(sm + (c & 3) * XBUFB);
#pragma unroll
        for (int ks = 0; ks < 2; ++ks) {
            const int ls0 = (ks << 3) + (fq << 1);     // x logical slot16
            const float4 xa = *(const float4*)(xb + ((R + fr) << 6) + ((ls0 ^ sw) << 2));
            const float4 xv = *(const float4*)(xb + ((R + fr) << 6) + (((ls0 + 1) ^ sw) << 2));
            f16x8 ah, al;
            split8(xa, xv, factor, ah, al);
            const f16x8 bh = ks ? bh1 : bh0;
            const f16x8 bl = ks ? bl1 : bl0;
            acch = __builtin_amdgcn_mfma_f32_16x16x32_f16(ah, bh, acch, 0, 0, 0);
            accm = __builtin_amdgcn_mfma_f32_16x16x32_f16(ah, bl, accm, 0, 0, 0);
            accm = __builtin_amdgcn_mfma_f32_16x16x32_f16(al, bh, accm, 0, 0, 0);
            accl = __builtin_amdgcn_mfma_f32_16x16x32_f16(al, bl, accl, 0, 0, 0);
        }
        // NO end-of-iter drain: next iter's top wait/barrier is the only sync
    }

    __syncthreads();                       // loop done; buffers dead

    // ---- epilogue: logits -> LDS [32][68] f32, then per-wave 4 rows ----
    float* lg = (float*)sm;
#pragma unroll
    for (int j = 0; j < 4; ++j) {
        const int rr = R + (fq << 2) + j;  // token row within 32-row tile
        lg[rr * 68 + CB + fr] = acch[j] + S1 * accm[j] + S2 * accl[j];
    }
    __syncthreads();

    const int r0 = w << 2;                 // 4 rows per wave (8 waves x 4 = 32)
#pragma unroll
    for (int i = 0; i < 4; ++i) {
        const int G = rowG0 + r0 + i;
        const float v = lg[(r0 + i) * 68 + l] + 0.1f * noise[(size_t)G * E + l];

        float m = v;
#pragma unroll
        for (int off = 32; off > 0; off >>= 1)
            m = fmaxf(m, __shfl_xor(m, off, 64));
        const float p = expf(v - m);
        float s = p;
#pragma unroll
        for (int off = 32; off > 0; off >>= 1)
            s += __shfl_xor(s, off, 64);
        const float prob = p / s;
        probs[(size_t)G * E + l] = prob;

        float bv = prob; int bi = l;
#pragma unroll
        for (int off = 32; off > 0; off >>= 1) {
            const float ov = __shfl_xor(bv, off, 64);
            const int   oi = __shfl_xor(bi, off, 64);
            if (ov > bv || (ov == bv && oi < bi)) { bv = ov; bi = oi; }
        }
        float cv = (l == bi) ? -INFINITY : prob;
        int ci = l;
#pragma unroll
        for (int off = 32; off > 0; off >>= 1) {
            const float ov = __shfl_xor(cv, off, 64);
            const int   oi = __shfl_xor(ci, off, 64);
            if (ov > cv || (ov == cv && oi < ci)) { cv = ov; ci = oi; }
        }

        const float sum2 = bv + cv;
        float dval = 0.f;
        if (l == bi) dval = bv / sum2;
        if (l == ci) dval = cv / sum2;
        dispatch[(size_t)G * E + l] = dval;

        if (l == 0) {
            float2 sv; sv.x = (float)bi; sv.y = (float)ci;
            *(float2*)(sel + (size_t)G * 2) = sv;
        }
    }
}

extern "C" void kernel_launch(void* const* d_in, const int* in_sizes, int n_in,
                              void* d_out, int out_size, void* d_ws, size_t ws_size,
                              hipStream_t stream) {
    const float* x     = (const float*)d_in[0];
    const float* W     = (const float*)d_in[1];
    const float* scond = (const float*)d_in[2];
    const float* noise = (const float*)d_in[3];
    const int*   sidx  = (const int*)d_in[4];

    float* out      = (float*)d_out;
    float* dispatch = out;
    float* probs    = out + (size_t)NROWS * E;
    float* sel      = out + 2 * (size_t)NROWS * E;

    (void)d_ws; (void)ws_size;   // workspace deliberately unused

    w_cvt<<<dim3(64), dim3(256), 0, stream>>>(W);
    moe_fused<<<dim3(NROWS / ROWS_PB), dim3(512), 0, stream>>>(
        x, scond, sidx, noise, dispatch, probs, sel);
}